// Round 23
// baseline (176.663 us; speedup 1.0000x reference)
//
#include <hip/hip_runtime.h>
#include <cstdint>
#include <cstddef>

typedef __bf16 bf16x8 __attribute__((ext_vector_type(8)));
typedef float f32x4 __attribute__((ext_vector_type(4)));
typedef int i32x4 __attribute__((ext_vector_type(4)));
typedef int i32x8 __attribute__((ext_vector_type(8)));

__device__ __forceinline__ void gload16(const void* g, void* l) {
  __builtin_amdgcn_global_load_lds((const __attribute__((address_space(1))) void*)g,
                                   (__attribute__((address_space(3))) void*)l, 16, 0, 0);
}

__device__ __forceinline__ float exp2_fast(float x) {
  float r;
  asm("v_exp_f32 %0, %1" : "=v"(r) : "v"(x));
  return r;
}
__device__ __forceinline__ float rcp_fast(float x) {
  float r;
  asm("v_rcp_f32 %0, %1" : "=v"(r) : "v"(x));
  return r;
}

// f32 -> OCP e4m3 (single value, low byte of packed cvt) -- hardware cvt, cheap
__device__ __forceinline__ unsigned char f32_to_fp8(float x) {
  int p = __builtin_amdgcn_cvt_pk_fp8_f32(x, 0.f, 0, false);
  return (unsigned char)(p & 0xff);
}

// f32 -> e2m1 fp4 code (weights only; cast once per call, amortized over consumers)
__device__ __forceinline__ unsigned int f32_to_fp4(float x) {
  const float a = fabsf(x);
  unsigned int c = a < 0.25f ? 0u : a < 0.75f ? 1u : a < 1.25f ? 2u : a < 1.75f ? 3u
                 : a < 2.5f  ? 4u : a < 3.5f  ? 5u : a < 5.0f  ? 6u : 7u;
  return c | ((__float_as_uint(x) >> 28) & 8u);
}
__device__ __forceinline__ unsigned char pack_fp4x2(float lo, float hi) {
  return (unsigned char)(f32_to_fp4(lo) | (f32_to_fp4(hi) << 4));
}

template<int N> __device__ __forceinline__ void wait_vm() {
  if constexpr (N == 0)       asm volatile("s_waitcnt vmcnt(0)" ::: "memory");
  else if constexpr (N == 4)  asm volatile("s_waitcnt vmcnt(4)" ::: "memory");
  else if constexpr (N == 5)  asm volatile("s_waitcnt vmcnt(5)" ::: "memory");
  else if constexpr (N == 9)  asm volatile("s_waitcnt vmcnt(9)" ::: "memory");
}

#define S_BARRIER() __builtin_amdgcn_s_barrier()
#define WAIT_LGKM() asm volatile("s_waitcnt lgkmcnt(0)" ::: "memory")

// ---------------- LayerNorm v2: one WAVE per row (no LDS, no barrier) ----------------
// fp32 in -> fp8 out, row = 768 = 12 elems/lane. 4 rows per 256-thread block; grid 2048.
__global__ __launch_bounds__(256) void ln_kernel(const float* __restrict__ x,
    const float* __restrict__ g, const float* __restrict__ b,
    unsigned char* __restrict__ out)
{
  const int row = blockIdx.x * 4 + (threadIdx.x >> 6);
  const int lane = threadIdx.x & 63;
  const float* xr = x + (size_t)row * 768;
  float v[12];
  float s = 0.f, q = 0.f;
  #pragma unroll
  for (int i = 0; i < 12; ++i) {
    v[i] = xr[lane + 64 * i];
    s += v[i];
    q += v[i] * v[i];
  }
  #pragma unroll
  for (int off = 32; off > 0; off >>= 1) {
    s += __shfl_xor(s, off, 64);
    q += __shfl_xor(q, off, 64);
  }
  const float mu = s * (1.0f / 768.0f);
  const float var = q * (1.0f / 768.0f) - mu * mu;
  const float rstd = rsqrtf(var + 1e-5f);
  unsigned char* orow = out + (size_t)row * 768;
  #pragma unroll
  for (int i = 0; i < 12; ++i) {
    const int c = lane + 64 * i;
    orow[c] = f32_to_fp8((v[i] - mu) * rstd * g[c] + b[c]);
  }
}

// ---------------- fused fp32 -> fp4 cast of all 4 weight matrices ----------------
// weights pre-scaled by wscale (128 or 256) before e2m1 quantize; the inverse
// power-of-2 is applied in HW via the MFMA B-scale operand.
__global__ __launch_bounds__(256) void cast4_kernel(
    const float* __restrict__ i0, const float* __restrict__ i1,
    const float* __restrict__ i2, const float* __restrict__ i3,
    unsigned char* __restrict__ o0, unsigned char* __restrict__ o1,
    unsigned char* __restrict__ o2, unsigned char* __restrict__ o3)
{
  const int n0 = 2304 * 768 / 4, n1 = 768 * 768 / 4;
  const int n2 = 3072 * 768 / 4, n3 = 768 * 3072 / 4;
  const int total = n0 + n1 + n2 + n3;
  for (int i = blockIdx.x * 256 + threadIdx.x; i < total; i += gridDim.x * 256) {
    const float* in; unsigned char* out; int j = i; float ws = 128.0f;
    if (j < n0) { in = i0; out = o0; }
    else if ((j -= n0) < n1) { in = i1; out = o1; }
    else if ((j -= n1) < n2) { in = i2; out = o2; }
    else { j -= n2; in = i3; out = o3; ws = 256.0f; }
    float4 v = ((const float4*)in)[j];
    const unsigned char b0 = pack_fp4x2(v.x * ws, v.y * ws);
    const unsigned char b1 = pack_fp4x2(v.z * ws, v.w * ws);
    ((unsigned short*)out)[j] = (unsigned short)(b0 | (b1 << 8));
  }
}

// ---------------- GEMM v14 (mixed A=fp8 / B=fp4, constexpr K, BM param) ------------
// BMx64 tile (BM=128 or 256), BK=128 elements, 4 waves (2x2),
// mfma_scale_f32_16x16x128_f8f6f4 with cbsz=0 (A fp8), blgp=4 (B fp4).
// BM=256 doubles MFMA per barrier-pair (16/wave) -- the r9/r11-validated
// barrier-amortization lever on the M axis. LDS 72 KB -> 2 blocks/CU (FC1/FC2).
// A fragments loaded per-fm inside the MFMA loop (1 live i32x8, not FM) to stay
// under the ~128-VGPR cap at 2 waves/SIMD (r13/r18/r20 spill lesson).
// NBUF=2, depth-1 counted prefetch, vmcnt(AG+1), granule XOR swizzles as r17.
// MODE 0: QKV scatter -> bf16. MODE 1: proj. MODE 2: fc1 (GELU -> fp8). MODE 3: fc2.
template<int MODE, int BM, int K, unsigned int SCALEB>
__global__ __launch_bounds__(256) void gemm_kernel(
    const unsigned char* __restrict__ A, const unsigned char* __restrict__ W,
    const float* __restrict__ bias, const float* __restrict__ resid,
    const float* __restrict__ ls, float* __restrict__ outf,
    unsigned char* __restrict__ outb,
    __bf16* __restrict__ qo, __bf16* __restrict__ ko, __bf16* __restrict__ vo)
{
  constexpr int FM = BM / 32;                  // 4 or 8 m-fragments per wave
  constexpr int FN = 2;
  constexpr int WMS = BM / 2;
  constexpr int AG = BM / 32;                  // A granules per thread per stage (4 or 8)
  constexpr int LPT = AG + 1;                  // global_load_lds per stage
  constexpr int ASTRIDE = BM * 128;            // A bytes per buffer
  constexpr int Kb2 = K >> 1;                  // W bytes per row
  constexpr int nk = K >> 7;                   // 6 or 24
  __shared__ unsigned char As[2 * ASTRIDE];    // 2 x 16/32 KB (fp8)
  __shared__ unsigned char Bs[2 * 64 * 64];    // 2 x 4 KB (fp4)

  // XCD-aware swizzle of the linear block id (bijective: nwg % 8 == 0)
  const int nx = gridDim.x;
  const int nwg = nx * gridDim.y;
  const int orig = blockIdx.x + nx * blockIdx.y;
  const int nid = (orig & 7) * (nwg >> 3) + (orig >> 3);
  const int bx = nid % nx, by = nid / nx;

  const int t = threadIdx.x;
  const int lane = t & 63;
  const int w = t >> 6;
  const int wm = w >> 1, wn = w & 1;
  const int m0 = by * BM, n0 = bx * 64;
  const int rl = lane & 15, gs = lane >> 4;

  f32x4 acc[FM][FN];
  #pragma unroll
  for (int i = 0; i < FM; ++i)
    #pragma unroll
    for (int j = 0; j < FN; ++j) acc[i][j] = { 0.f, 0.f, 0.f, 0.f };

  // A staging: 8 granules per 128B row-slab, AG per thread; pre-swizzled source
  const unsigned char* Asrc[AG];
  #pragma unroll
  for (int i = 0; i < AG; ++i) {
    const int g = i * 256 + t, row = g >> 3, gc = g & 7;
    Asrc[i] = A + (size_t)(m0 + row) * K + ((gc ^ (row & 7)) << 4);
  }
  // B staging: 4 granules per 64B row-slab, 1 per thread
  const unsigned char* Bsrc1;
  {
    const int row = t >> 2, gc = t & 3;
    Bsrc1 = W + (size_t)(n0 + row) * Kb2 + ((gc ^ (row & 3)) << 4);
  }

  auto stage = [&](int kt, int buf) {
    const int ka = kt << 7;                    // A: 128 B per K-tile
    const int kb = kt << 6;                    // B: 64 B per K-tile
    #pragma unroll
    for (int i = 0; i < AG; ++i)
      gload16(Asrc[i] + ka, As + buf * ASTRIDE + (i * 256 + t) * 16);
    gload16(Bsrc1 + kb, Bs + buf * 4096 + t * 16);
  };

  // A fragment: lane's 32 fp8 (k = gs*32..gs*32+31) via 2 swizzled b128 reads
  auto ldA = [&](const unsigned char* rowbase, int sw) -> i32x8 {
    const i32x4 lo = *(const i32x4*)(rowbase + (((2 * gs + 0) ^ sw) << 4));
    const i32x4 hi = *(const i32x4*)(rowbase + (((2 * gs + 1) ^ sw) << 4));
    i32x8 r;
    r[0] = lo[0]; r[1] = lo[1]; r[2] = lo[2]; r[3] = lo[3];
    r[4] = hi[0]; r[5] = hi[1]; r[6] = hi[2]; r[7] = hi[3];
    return r;
  };
  // B fragment: lane's 32 fp4 (16 B) via 1 swizzled b128 read
  auto ldB = [&](const unsigned char* rowbase, int sw) -> i32x8 {
    const i32x4 v = *(const i32x4*)(rowbase + ((gs ^ sw) << 4));
    i32x8 r;
    r[0] = v[0]; r[1] = v[1]; r[2] = v[2]; r[3] = v[3];
    r[4] = 0; r[5] = 0; r[6] = 0; r[7] = 0;
    return r;
  };

  stage(0, 0);

  #pragma unroll 2
  for (int kt = 0; kt < nk; ++kt) {
    const int cur = kt & 1;
    if (kt + 1 < nk) { stage(kt + 1, cur ^ 1); wait_vm<LPT>(); }
    else             { wait_vm<0>(); }
    S_BARRIER();                  // tile kt resident for all waves

    const unsigned char* Ac = As + cur * ASTRIDE;
    const unsigned char* Bc = Bs + cur * 4096;
    i32x8 bfr[FN];
    #pragma unroll
    for (int fn = 0; fn < FN; ++fn) {
      const int row = wn * 32 + fn * 16 + rl;
      bfr[fn] = ldB(Bc + row * 64, row & 3);
    }
    #pragma unroll
    for (int fm = 0; fm < FM; ++fm) {
      const int row = wm * WMS + fm * 16 + rl;
      const i32x8 af = ldA(Ac + row * 128, row & 7);
      #pragma unroll
      for (int fn = 0; fn < FN; ++fn)
        acc[fm][fn] = __builtin_amdgcn_mfma_scale_f32_16x16x128_f8f6f4(
            af, bfr[fn], acc[fm][fn],
            0, 4,                       // cbsz: A=fp8, blgp: B=fp4
            0, 0x7F7F7F7F,              // A scale = 1.0
            0, (int)SCALEB);            // B scale = 2^-7 / 2^-8
    }

    S_BARRIER();                  // all waves done with tile kt before re-staging
  }

  // epilogue: C row = m0+wm*WMS+fm*16+gs*4+b ; col = n0+wn*32+fn*16+rl
  #pragma unroll
  for (int fm = 0; fm < FM; ++fm) {
    const int rbase = m0 + wm * WMS + fm * 16 + gs * 4;
    #pragma unroll
    for (int fn = 0; fn < FN; ++fn) {
      const int c = n0 + wn * 32 + fn * 16 + rl;
      #pragma unroll
      for (int b = 0; b < 4; ++b) {
        const int r = rbase + b;
        const float val = acc[fm][fn][b];
        if constexpr (MODE == 0) {
          const int sec = c / 768;
          const int cc = c - sec * 768;
          const int hh = cc >> 6, d = cc & 63;
          const int batch = r >> 10, n = r & 1023;
          const size_t bh = (size_t)(batch * 12 + hh);
          // Q scaled by (1/8)*log2(e) so softmax uses raw v_exp_f32 (2^x)
          if (sec == 0)      qo[(bh * 1024 + n) * 64 + d] = (__bf16)(val * 0.1803368801111204f);
          else if (sec == 1) ko[(bh * 1024 + n) * 64 + d] = (__bf16)val;
          else               vo[(bh * 64 + d) * 1024 + n] = (__bf16)val;
        } else if constexpr (MODE == 1) {
          const size_t idx = (size_t)r * 768 + c;
          outf[idx] = resid[idx] + ls[c] * (val + bias[c]);
        } else if constexpr (MODE == 2) {
          // fast GELU -> fp8 byte store (hardware cvt; no shfl, no lane masking)
          const float h = val + bias[c];
          const float z = h * (1.0f + 0.044715f * h * h);
          const float e = exp2_fast(2.3021181f * z);
          const float gl = h - h * rcp_fast(1.0f + e);
          outb[(size_t)r * 3072 + c] = f32_to_fp8(gl);
        } else {
          const size_t idx = (size_t)r * 768 + c;
          outf[idx] = resid[idx] + ls[c] * (val + bias[c]);
        }
      }
    }
  }
}

// ---------------- Flash attention (r14/r17 known-good: K+V LDS-staged, fp8 out) ----
// Q: [96][1024][64] bf16 pre-scaled by 0.125*log2e. K: [96][1024][64]. Vt: [96][64][1024].
// Fixed-max exp2 softmax, deferred denominator. Output fp8 (proj's A input).
// Head-locality XCD mapping (bh%8 == nid%8).
// NOTE: sharp register-space local optimum -- r13/r18/r20 variants all spilled.
// Keep launch_bounds(256,3).
__global__ __launch_bounds__(256, 3) void attn_kernel(
    const __bf16* __restrict__ Q, const __bf16* __restrict__ Kb,
    const __bf16* __restrict__ Vt, unsigned char* __restrict__ Ob)
{
  __shared__ __bf16 Ks[2][64 * 64];     // 2 x 8 KB
  __shared__ __bf16 Vs[2][64 * 64];     // 2 x 8 KB
  __shared__ __bf16 P_lds[4][32 * 72];  // per-wave P, rows padded to 72 halves (18 KB)

  const int nid = blockIdx.x;
  const int b7 = nid & 7, rest = nid >> 3;
  const int qt = rest & 7;
  const int bh = b7 + ((rest >> 3) << 3);

  const int t = threadIdx.x, lane = t & 63, w = t >> 6;
  const int rl = lane & 15, gs = lane >> 4;
  const int q0 = qt * 128 + w * 32;
  const __bf16* Qh = Q  + (size_t)bh * 1024 * 64;
  const char*   Kg = (const char*)(Kb + (size_t)bh * 1024 * 64);
  const char*   Vg = (const char*)(Vt + (size_t)bh * 64 * 1024);
  __bf16* Pw = &P_lds[w][0];

  const int g0 = w * 64 + lane;         // 0..255
  const int g1 = 256 + g0;              // 256..511
  const int r0 = g0 >> 3, sb0 = (g0 & 7) ^ (r0 & 7);
  const int r1 = g1 >> 3, sb1 = (g1 & 7) ^ (r1 & 7);

  bf16x8 aq[2][2];
  #pragma unroll
  for (int m = 0; m < 2; ++m)
    #pragma unroll
    for (int ks = 0; ks < 2; ++ks)
      aq[m][ks] = *(const bf16x8*)(Qh + (size_t)(q0 + m * 16 + rl) * 64 + ks * 32 + gs * 8);

  f32x4 accO[2][4];
  #pragma unroll
  for (int m = 0; m < 2; ++m)
    #pragma unroll
    for (int d = 0; d < 4; ++d) accO[m][d] = { 0.f, 0.f, 0.f, 0.f };
  float L[2][4];
  #pragma unroll
  for (int m = 0; m < 2; ++m)
    #pragma unroll
    for (int b = 0; b < 4; ++b) L[m][b] = 0.f;

  {
    gload16(Kg + (size_t)r0 * 128 + sb0 * 16, (char*)Ks[0] + g0 * 16);
    gload16(Kg + (size_t)r1 * 128 + sb1 * 16, (char*)Ks[0] + g1 * 16);
    gload16(Vg + (size_t)r0 * 2048 + sb0 * 16, (char*)Vs[0] + g0 * 16);
    gload16(Vg + (size_t)r1 * 2048 + sb1 * 16, (char*)Vs[0] + g1 * 16);
  }

  for (int tile = 0; tile < 16; ++tile) {
    const int cur = tile & 1;
    if (tile + 1 < 16) {
      const int nxt = cur ^ 1;
      const size_t kofs = (size_t)(tile + 1) * 64;
      gload16(Kg + (kofs + r0) * 128 + sb0 * 16, (char*)Ks[nxt] + g0 * 16);
      gload16(Kg + (kofs + r1) * 128 + sb1 * 16, (char*)Ks[nxt] + g1 * 16);
      gload16(Vg + (size_t)r0 * 2048 + kofs * 2 + sb0 * 16, (char*)Vs[nxt] + g0 * 16);
      gload16(Vg + (size_t)r1 * 2048 + kofs * 2 + sb1 * 16, (char*)Vs[nxt] + g1 * 16);
      wait_vm<4>();   // current tile's 4 loads landed; next tile's stay in flight
    } else {
      wait_vm<0>();
    }
    S_BARRIER();

    const __bf16* Kc = Ks[cur];
    const __bf16* Vc = Vs[cur];

    f32x4 s[2][4];
    #pragma unroll
    for (int m = 0; m < 2; ++m)
      #pragma unroll
      for (int ct = 0; ct < 4; ++ct) s[m][ct] = { 0.f, 0.f, 0.f, 0.f };
    __builtin_amdgcn_s_setprio(1);
    #pragma unroll
    for (int ct = 0; ct < 4; ++ct) {
      #pragma unroll
      for (int ks = 0; ks < 2; ++ks) {
        const int row = ct * 16 + rl;
        const int blk = (ks * 4 + gs) ^ (row & 7);
        bf16x8 kf = *(const bf16x8*)(Kc + row * 64 + blk * 8);
        s[0][ct] = __builtin_amdgcn_mfma_f32_16x16x32_bf16(aq[0][ks], kf, s[0][ct], 0, 0, 0);
        s[1][ct] = __builtin_amdgcn_mfma_f32_16x16x32_bf16(aq[1][ks], kf, s[1][ct], 0, 0, 0);
      }
    }
    __builtin_amdgcn_s_setprio(0);

    #pragma unroll
    for (int m = 0; m < 2; ++m) {
      #pragma unroll
      for (int b = 0; b < 4; ++b) {
        float rs = 0.f;
        #pragma unroll
        for (int ct = 0; ct < 4; ++ct) {
          const float p = exp2_fast(s[m][ct][b]);
          rs += p;
          Pw[(m * 16 + gs * 4 + b) * 72 + ct * 16 + rl] = (__bf16)p;
        }
        L[m][b] += rs;
      }
    }

    WAIT_LGKM();
    bf16x8 ap[2][2];
    #pragma unroll
    for (int m = 0; m < 2; ++m)
      #pragma unroll
      for (int ks = 0; ks < 2; ++ks)
        ap[m][ks] = *(const bf16x8*)(Pw + (m * 16 + rl) * 72 + ks * 32 + gs * 8);

    __builtin_amdgcn_s_setprio(1);
    #pragma unroll
    for (int dt = 0; dt < 4; ++dt) {
      #pragma unroll
      for (int ks = 0; ks < 2; ++ks) {
        const int row = dt * 16 + rl;
        const int blk = (ks * 4 + gs) ^ (row & 7);
        bf16x8 vf = *(const bf16x8*)(Vc + row * 64 + blk * 8);
        accO[0][dt] = __builtin_amdgcn_mfma_f32_16x16x32_bf16(ap[0][ks], vf, accO[0][dt], 0, 0, 0);
        accO[1][dt] = __builtin_amdgcn_mfma_f32_16x16x32_bf16(ap[1][ks], vf, accO[1][dt], 0, 0, 0);
      }
    }
    __builtin_amdgcn_s_setprio(0);

    S_BARRIER();
  }

  float invL[2][4];
  #pragma unroll
  for (int m = 0; m < 2; ++m)
    #pragma unroll
    for (int b = 0; b < 4; ++b) {
      float rs = L[m][b];
      #pragma unroll
      for (int off = 1; off < 16; off <<= 1) rs += __shfl_xor(rs, off, 16);
      invL[m][b] = 1.0f / rs;
    }

  const int batch = bh / 12, hh = bh - batch * 12;
  #pragma unroll
  for (int m = 0; m < 2; ++m) {
    const size_t rowbase = (size_t)batch * 1024 + qt * 128 + w * 32 + m * 16 + gs * 4;
    #pragma unroll
    for (int dt = 0; dt < 4; ++dt)
      #pragma unroll
      for (int b = 0; b < 4; ++b)
        Ob[(rowbase + b) * 768 + hh * 64 + dt * 16 + rl] = f32_to_fp8(accO[m][dt][b] * invL[m][b]);
  }
}

// ---------------- launch ----------------
extern "C" void kernel_launch(void* const* d_in, const int* in_sizes, int n_in,
                              void* d_out, int out_size, void* d_ws, size_t ws_size,
                              hipStream_t stream) {
  const float* x      = (const float*)d_in[0];
  const float* ln1_g  = (const float*)d_in[1];
  const float* ln1_b  = (const float*)d_in[2];
  const float* w_qkv  = (const float*)d_in[3];
  const float* w_proj = (const float*)d_in[4];
  const float* b_proj = (const float*)d_in[5];
  const float* ls1    = (const float*)d_in[6];
  const float* ln2_g  = (const float*)d_in[7];
  const float* ln2_b  = (const float*)d_in[8];
  const float* w_fc1  = (const float*)d_in[9];
  const float* b_fc1  = (const float*)d_in[10];
  const float* w_fc2  = (const float*)d_in[11];
  const float* b_fc2  = (const float*)d_in[12];
  const float* ls2    = (const float*)d_in[13];
  float* out = (float*)d_out;

  char* ws = (char*)d_ws;
  size_t off = 0;
  auto alloc = [&](size_t bytes) { char* p = ws + off; off += (bytes + 255) & ~(size_t)255; return p; };
  unsigned char* h1    = (unsigned char*)alloc(8192ull * 768);      // LN1 out (fp8); later attn_out (fp8)
  unsigned char* wqkv4 = (unsigned char*)alloc(2304ull * 384);
  unsigned char* wprj4 = (unsigned char*)alloc(768ull * 384);
  unsigned char* wfc14 = (unsigned char*)alloc(3072ull * 384);
  unsigned char* wfc24 = (unsigned char*)alloc(768ull * 1536);
  __bf16* Qb    = (__bf16*)alloc(8192ull * 768 * 2);
  __bf16* Kb    = (__bf16*)alloc(8192ull * 768 * 2);
  __bf16* Vt    = (__bf16*)alloc(8192ull * 768 * 2);
  float*  out1  = (float*)alloc(8192ull * 768 * 4);
  unsigned char* fc1o = (unsigned char*)alloc(8192ull * 3072);      // fp8
  unsigned char* h2   = (unsigned char*)alloc(8192ull * 768);       // LN2 out (fp8)

  constexpr unsigned int SC7 = 0x78787878u;   // e8m0 2^-7 (weights quantized at x128)
  constexpr unsigned int SC8 = 0x77777777u;   // e8m0 2^-8 (fc2 quantized at x256)

  ln_kernel<<<2048, 256, 0, stream>>>(x, ln1_g, ln1_b, h1);
  cast4_kernel<<<2048, 256, 0, stream>>>(w_qkv, w_proj, w_fc1, w_fc2,
                                         wqkv4, wprj4, wfc14, wfc24);

  gemm_kernel<0, 128, 768, SC7><<<dim3(36, 64), 256, 0, stream>>>(h1, wqkv4,
      nullptr, nullptr, nullptr, nullptr, nullptr, Qb, Kb, Vt);

  attn_kernel<<<96 * 8, 256, 0, stream>>>(Qb, Kb, Vt, h1);  // h1 = attn_out (fp8) now

  gemm_kernel<1, 128, 768, SC7><<<dim3(12, 64), 256, 0, stream>>>(h1, wprj4,
      b_proj, x, ls1, out1, nullptr, nullptr, nullptr, nullptr);

  ln_kernel<<<2048, 256, 0, stream>>>(out1, ln2_g, ln2_b, h2);

  gemm_kernel<2, 256, 768, SC7><<<dim3(48, 32), 256, 0, stream>>>(h2, wfc14,
      b_fc1, nullptr, nullptr, nullptr, fc1o, nullptr, nullptr, nullptr);

  gemm_kernel<3, 256, 3072, SC8><<<dim3(12, 32), 256, 0, stream>>>(fc1o, wfc24,
      b_fc2, out1, ls2, out, nullptr, nullptr, nullptr, nullptr);
}

// Round 24
// 171.071 us; speedup vs baseline: 1.0327x; 1.0327x over previous
//
#include <hip/hip_runtime.h>
#include <cstdint>
#include <cstddef>

typedef __bf16 bf16x8 __attribute__((ext_vector_type(8)));
typedef float f32x4 __attribute__((ext_vector_type(4)));
typedef int i32x4 __attribute__((ext_vector_type(4)));
typedef int i32x8 __attribute__((ext_vector_type(8)));

__device__ __forceinline__ void gload16(const void* g, void* l) {
  __builtin_amdgcn_global_load_lds((const __attribute__((address_space(1))) void*)g,
                                   (__attribute__((address_space(3))) void*)l, 16, 0, 0);
}

__device__ __forceinline__ float exp2_fast(float x) {
  float r;
  asm("v_exp_f32 %0, %1" : "=v"(r) : "v"(x));
  return r;
}
__device__ __forceinline__ float rcp_fast(float x) {
  float r;
  asm("v_rcp_f32 %0, %1" : "=v"(r) : "v"(x));
  return r;
}

// f32 -> OCP e4m3 (single value, low byte of packed cvt) -- hardware cvt, cheap
__device__ __forceinline__ unsigned char f32_to_fp8(float x) {
  int p = __builtin_amdgcn_cvt_pk_fp8_f32(x, 0.f, 0, false);
  return (unsigned char)(p & 0xff);
}

// f32 -> e2m1 fp4 code (weights only; cast once per call, amortized over consumers)
__device__ __forceinline__ unsigned int f32_to_fp4(float x) {
  const float a = fabsf(x);
  unsigned int c = a < 0.25f ? 0u : a < 0.75f ? 1u : a < 1.25f ? 2u : a < 1.75f ? 3u
                 : a < 2.5f  ? 4u : a < 3.5f  ? 5u : a < 5.0f  ? 6u : 7u;
  return c | ((__float_as_uint(x) >> 28) & 8u);
}
__device__ __forceinline__ unsigned char pack_fp4x2(float lo, float hi) {
  return (unsigned char)(f32_to_fp4(lo) | (f32_to_fp4(hi) << 4));
}

template<int N> __device__ __forceinline__ void wait_vm() {
  if constexpr (N == 0)       asm volatile("s_waitcnt vmcnt(0)" ::: "memory");
  else if constexpr (N == 4)  asm volatile("s_waitcnt vmcnt(4)" ::: "memory");
  else if constexpr (N == 5)  asm volatile("s_waitcnt vmcnt(5)" ::: "memory");
}

#define S_BARRIER() __builtin_amdgcn_s_barrier()
#define WAIT_LGKM() asm volatile("s_waitcnt lgkmcnt(0)" ::: "memory")

// ---------------- LayerNorm v2: one WAVE per row (no LDS, no barrier) ----------------
// fp32 in -> fp8 out, row = 768 = 12 elems/lane. 4 rows per 256-thread block; grid 2048.
__global__ __launch_bounds__(256) void ln_kernel(const float* __restrict__ x,
    const float* __restrict__ g, const float* __restrict__ b,
    unsigned char* __restrict__ out)
{
  const int row = blockIdx.x * 4 + (threadIdx.x >> 6);
  const int lane = threadIdx.x & 63;
  const float* xr = x + (size_t)row * 768;
  float v[12];
  float s = 0.f, q = 0.f;
  #pragma unroll
  for (int i = 0; i < 12; ++i) {
    v[i] = xr[lane + 64 * i];
    s += v[i];
    q += v[i] * v[i];
  }
  #pragma unroll
  for (int off = 32; off > 0; off >>= 1) {
    s += __shfl_xor(s, off, 64);
    q += __shfl_xor(q, off, 64);
  }
  const float mu = s * (1.0f / 768.0f);
  const float var = q * (1.0f / 768.0f) - mu * mu;
  const float rstd = rsqrtf(var + 1e-5f);
  unsigned char* orow = out + (size_t)row * 768;
  #pragma unroll
  for (int i = 0; i < 12; ++i) {
    const int c = lane + 64 * i;
    orow[c] = f32_to_fp8((v[i] - mu) * rstd * g[c] + b[c]);
  }
}

// ---------------- fused fp32 -> fp4 cast of all 4 weight matrices ----------------
// weights pre-scaled by wscale (128 or 256) before e2m1 quantize; the inverse
// power-of-2 is applied in HW via the MFMA B-scale operand.
__global__ __launch_bounds__(256) void cast4_kernel(
    const float* __restrict__ i0, const float* __restrict__ i1,
    const float* __restrict__ i2, const float* __restrict__ i3,
    unsigned char* __restrict__ o0, unsigned char* __restrict__ o1,
    unsigned char* __restrict__ o2, unsigned char* __restrict__ o3)
{
  const int n0 = 2304 * 768 / 4, n1 = 768 * 768 / 4;
  const int n2 = 3072 * 768 / 4, n3 = 768 * 3072 / 4;
  const int total = n0 + n1 + n2 + n3;
  for (int i = blockIdx.x * 256 + threadIdx.x; i < total; i += gridDim.x * 256) {
    const float* in; unsigned char* out; int j = i; float ws = 128.0f;
    if (j < n0) { in = i0; out = o0; }
    else if ((j -= n0) < n1) { in = i1; out = o1; }
    else if ((j -= n1) < n2) { in = i2; out = o2; }
    else { j -= n2; in = i3; out = o3; ws = 256.0f; }
    float4 v = ((const float4*)in)[j];
    const unsigned char b0 = pack_fp4x2(v.x * ws, v.y * ws);
    const unsigned char b1 = pack_fp4x2(v.z * ws, v.w * ws);
    ((unsigned short*)out)[j] = (unsigned short)(b0 | (b1 << 8));
  }
}

// ---------------- GEMM v13 (mixed A=fp8 / B=fp4, constexpr K): C = A @ W^T ----------
// 128x64 tile, BK=128 elements (A-row 128 B, B-row 64 B), 4 waves (2x2),
// mfma_scale_f32_16x16x128_f8f6f4 with cbsz=0 (A fp8), blgp=4 (B fp4).
// K and SCALEB are template params: nk constexpr -> no loop-carried compares,
// hoisted addressing. NBUF=2, depth-1 counted prefetch, vmcnt(5), 40 KB LDS.
// A: 16B-granule XOR swizzle gc^=row&7. B: gc^=row&3. XCD-aware block swizzle.
// MODE 0: QKV scatter -> bf16 (Q scaled 0.125*log2e, V transposed).
// MODE 1: proj (+bias, resid+ls -> f32). MODE 2: fc1 (+bias, fast GELU -> fp8).
// MODE 3: fc2 (+bias, resid+ls -> f32).
template<int MODE, int K, unsigned int SCALEB>
__global__ __launch_bounds__(256) void gemm_kernel(
    const unsigned char* __restrict__ A, const unsigned char* __restrict__ W,
    const float* __restrict__ bias, const float* __restrict__ resid,
    const float* __restrict__ ls, float* __restrict__ outf,
    unsigned char* __restrict__ outb,
    __bf16* __restrict__ qo, __bf16* __restrict__ ko, __bf16* __restrict__ vo)
{
  constexpr int FM = 4, FN = 2;
  constexpr int Kb2 = K >> 1;                  // W bytes per row
  constexpr int nk = K >> 7;                   // 6 (K=768) or 24 (K=3072)
  __shared__ unsigned char As[2 * 128 * 128];  // 2 x 16 KB (fp8)
  __shared__ unsigned char Bs[2 * 64 * 64];    // 2 x 4 KB  (fp4)

  // XCD-aware swizzle of the linear block id (bijective: nwg % 8 == 0)
  const int nx = gridDim.x;
  const int nwg = nx * gridDim.y;
  const int orig = blockIdx.x + nx * blockIdx.y;
  const int nid = (orig & 7) * (nwg >> 3) + (orig >> 3);
  const int bx = nid % nx, by = nid / nx;

  const int t = threadIdx.x;
  const int lane = t & 63;
  const int w = t >> 6;
  const int wm = w >> 1, wn = w & 1;
  const int m0 = by * 128, n0 = bx * 64;
  const int rl = lane & 15, gs = lane >> 4;

  f32x4 acc[FM][FN];
  #pragma unroll
  for (int i = 0; i < FM; ++i)
    #pragma unroll
    for (int j = 0; j < FN; ++j) acc[i][j] = { 0.f, 0.f, 0.f, 0.f };

  // A staging: 8 granules per 128B row-slab, 4 per thread; pre-swizzled source
  const unsigned char* Asrc[4];
  #pragma unroll
  for (int i = 0; i < 4; ++i) {
    const int g = i * 256 + t, row = g >> 3, gc = g & 7;
    Asrc[i] = A + (size_t)(m0 + row) * K + ((gc ^ (row & 7)) << 4);
  }
  // B staging: 4 granules per 64B row-slab, 1 per thread
  const unsigned char* Bsrc1;
  {
    const int row = t >> 2, gc = t & 3;
    Bsrc1 = W + (size_t)(n0 + row) * Kb2 + ((gc ^ (row & 3)) << 4);
  }

  auto stage = [&](int kt, int buf) {
    const int ka = kt << 7;                    // A: 128 B per K-tile
    const int kb = kt << 6;                    // B: 64 B per K-tile
    #pragma unroll
    for (int i = 0; i < 4; ++i)
      gload16(Asrc[i] + ka, As + buf * 16384 + (i * 256 + t) * 16);
    gload16(Bsrc1 + kb, Bs + buf * 4096 + t * 16);
  };

  // A fragment: lane's 32 fp8 (k = gs*32..gs*32+31) via 2 swizzled b128 reads
  auto ldA = [&](const unsigned char* rowbase, int sw) -> i32x8 {
    const i32x4 lo = *(const i32x4*)(rowbase + (((2 * gs + 0) ^ sw) << 4));
    const i32x4 hi = *(const i32x4*)(rowbase + (((2 * gs + 1) ^ sw) << 4));
    i32x8 r;
    r[0] = lo[0]; r[1] = lo[1]; r[2] = lo[2]; r[3] = lo[3];
    r[4] = hi[0]; r[5] = hi[1]; r[6] = hi[2]; r[7] = hi[3];
    return r;
  };
  // B fragment: lane's 32 fp4 (16 B) via 1 swizzled b128 read
  auto ldB = [&](const unsigned char* rowbase, int sw) -> i32x8 {
    const i32x4 v = *(const i32x4*)(rowbase + ((gs ^ sw) << 4));
    i32x8 r;
    r[0] = v[0]; r[1] = v[1]; r[2] = v[2]; r[3] = v[3];
    r[4] = 0; r[5] = 0; r[6] = 0; r[7] = 0;
    return r;
  };

  stage(0, 0);

  #pragma unroll 2
  for (int kt = 0; kt < nk; ++kt) {
    const int cur = kt & 1;
    if (kt + 1 < nk) { stage(kt + 1, cur ^ 1); wait_vm<5>(); }
    else             { wait_vm<0>(); }
    S_BARRIER();                  // tile kt resident for all waves

    const unsigned char* Ac = As + cur * 16384;
    const unsigned char* Bc = Bs + cur * 4096;
    i32x8 af[FM], bfr[FN];
    #pragma unroll
    for (int fm = 0; fm < FM; ++fm) {
      const int row = wm * 64 + fm * 16 + rl;
      af[fm] = ldA(Ac + row * 128, row & 7);
    }
    #pragma unroll
    for (int fn = 0; fn < FN; ++fn) {
      const int row = wn * 32 + fn * 16 + rl;
      bfr[fn] = ldB(Bc + row * 64, row & 3);
    }
    #pragma unroll
    for (int fm = 0; fm < FM; ++fm)
      #pragma unroll
      for (int fn = 0; fn < FN; ++fn)
        acc[fm][fn] = __builtin_amdgcn_mfma_scale_f32_16x16x128_f8f6f4(
            af[fm], bfr[fn], acc[fm][fn],
            0, 4,                       // cbsz: A=fp8, blgp: B=fp4
            0, 0x7F7F7F7F,              // A scale = 1.0
            0, (int)SCALEB);            // B scale = 2^-7 / 2^-8

    S_BARRIER();                  // all waves done with tile kt before re-staging
  }

  // epilogue: C row = m0+wm*64+fm*16+gs*4+b ; col = n0+wn*32+fn*16+rl
  #pragma unroll
  for (int fm = 0; fm < FM; ++fm) {
    const int rbase = m0 + wm * 64 + fm * 16 + gs * 4;
    #pragma unroll
    for (int fn = 0; fn < FN; ++fn) {
      const int c = n0 + wn * 32 + fn * 16 + rl;
      #pragma unroll
      for (int b = 0; b < 4; ++b) {
        const int r = rbase + b;
        const float val = acc[fm][fn][b];
        if constexpr (MODE == 0) {
          const int sec = c / 768;
          const int cc = c - sec * 768;
          const int hh = cc >> 6, d = cc & 63;
          const int batch = r >> 10, n = r & 1023;
          const size_t bh = (size_t)(batch * 12 + hh);
          // Q scaled by (1/8)*log2(e) so softmax uses raw v_exp_f32 (2^x)
          if (sec == 0)      qo[(bh * 1024 + n) * 64 + d] = (__bf16)(val * 0.1803368801111204f);
          else if (sec == 1) ko[(bh * 1024 + n) * 64 + d] = (__bf16)val;
          else               vo[(bh * 64 + d) * 1024 + n] = (__bf16)val;
        } else if constexpr (MODE == 1) {
          const size_t idx = (size_t)r * 768 + c;
          outf[idx] = resid[idx] + ls[c] * (val + bias[c]);
        } else if constexpr (MODE == 2) {
          // fast GELU -> fp8 byte store (hardware cvt; no shfl, no lane masking)
          const float h = val + bias[c];
          const float z = h * (1.0f + 0.044715f * h * h);
          const float e = exp2_fast(2.3021181f * z);
          const float gl = h - h * rcp_fast(1.0f + e);
          outb[(size_t)r * 3072 + c] = f32_to_fp8(gl);
        } else {
          const size_t idx = (size_t)r * 768 + c;
          outf[idx] = resid[idx] + ls[c] * (val + bias[c]);
        }
      }
    }
  }
}

// ---------------- Flash attention (r14/r17 known-good: K+V LDS-staged, fp8 out) ----
// Q: [96][1024][64] bf16 pre-scaled by 0.125*log2e. K: [96][1024][64]. Vt: [96][64][1024].
// Fixed-max exp2 softmax, deferred denominator. Output fp8 (proj's A input).
// Head-locality XCD mapping (bh%8 == nid%8).
// NOTE: sharp register-space local optimum -- r13/r18/r20 variants all spilled
// (WRITE_SIZE 20-220 MB) and regressed 1.7-2.3x. Keep launch_bounds(256,3).
__global__ __launch_bounds__(256, 3) void attn_kernel(
    const __bf16* __restrict__ Q, const __bf16* __restrict__ Kb,
    const __bf16* __restrict__ Vt, unsigned char* __restrict__ Ob)
{
  __shared__ __bf16 Ks[2][64 * 64];     // 2 x 8 KB
  __shared__ __bf16 Vs[2][64 * 64];     // 2 x 8 KB
  __shared__ __bf16 P_lds[4][32 * 72];  // per-wave P, rows padded to 72 halves (18 KB)

  const int nid = blockIdx.x;
  const int b7 = nid & 7, rest = nid >> 3;
  const int qt = rest & 7;
  const int bh = b7 + ((rest >> 3) << 3);

  const int t = threadIdx.x, lane = t & 63, w = t >> 6;
  const int rl = lane & 15, gs = lane >> 4;
  const int q0 = qt * 128 + w * 32;
  const __bf16* Qh = Q  + (size_t)bh * 1024 * 64;
  const char*   Kg = (const char*)(Kb + (size_t)bh * 1024 * 64);
  const char*   Vg = (const char*)(Vt + (size_t)bh * 64 * 1024);
  __bf16* Pw = &P_lds[w][0];

  const int g0 = w * 64 + lane;         // 0..255
  const int g1 = 256 + g0;              // 256..511
  const int r0 = g0 >> 3, sb0 = (g0 & 7) ^ (r0 & 7);
  const int r1 = g1 >> 3, sb1 = (g1 & 7) ^ (r1 & 7);

  bf16x8 aq[2][2];
  #pragma unroll
  for (int m = 0; m < 2; ++m)
    #pragma unroll
    for (int ks = 0; ks < 2; ++ks)
      aq[m][ks] = *(const bf16x8*)(Qh + (size_t)(q0 + m * 16 + rl) * 64 + ks * 32 + gs * 8);

  f32x4 accO[2][4];
  #pragma unroll
  for (int m = 0; m < 2; ++m)
    #pragma unroll
    for (int d = 0; d < 4; ++d) accO[m][d] = { 0.f, 0.f, 0.f, 0.f };
  float L[2][4];
  #pragma unroll
  for (int m = 0; m < 2; ++m)
    #pragma unroll
    for (int b = 0; b < 4; ++b) L[m][b] = 0.f;

  {
    gload16(Kg + (size_t)r0 * 128 + sb0 * 16, (char*)Ks[0] + g0 * 16);
    gload16(Kg + (size_t)r1 * 128 + sb1 * 16, (char*)Ks[0] + g1 * 16);
    gload16(Vg + (size_t)r0 * 2048 + sb0 * 16, (char*)Vs[0] + g0 * 16);
    gload16(Vg + (size_t)r1 * 2048 + sb1 * 16, (char*)Vs[0] + g1 * 16);
  }

  for (int tile = 0; tile < 16; ++tile) {
    const int cur = tile & 1;
    if (tile + 1 < 16) {
      const int nxt = cur ^ 1;
      const size_t kofs = (size_t)(tile + 1) * 64;
      gload16(Kg + (kofs + r0) * 128 + sb0 * 16, (char*)Ks[nxt] + g0 * 16);
      gload16(Kg + (kofs + r1) * 128 + sb1 * 16, (char*)Ks[nxt] + g1 * 16);
      gload16(Vg + (size_t)r0 * 2048 + kofs * 2 + sb0 * 16, (char*)Vs[nxt] + g0 * 16);
      gload16(Vg + (size_t)r1 * 2048 + kofs * 2 + sb1 * 16, (char*)Vs[nxt] + g1 * 16);
      wait_vm<4>();   // current tile's 4 loads landed; next tile's stay in flight
    } else {
      wait_vm<0>();
    }
    S_BARRIER();

    const __bf16* Kc = Ks[cur];
    const __bf16* Vc = Vs[cur];

    f32x4 s[2][4];
    #pragma unroll
    for (int m = 0; m < 2; ++m)
      #pragma unroll
      for (int ct = 0; ct < 4; ++ct) s[m][ct] = { 0.f, 0.f, 0.f, 0.f };
    __builtin_amdgcn_s_setprio(1);
    #pragma unroll
    for (int ct = 0; ct < 4; ++ct) {
      #pragma unroll
      for (int ks = 0; ks < 2; ++ks) {
        const int row = ct * 16 + rl;
        const int blk = (ks * 4 + gs) ^ (row & 7);
        bf16x8 kf = *(const bf16x8*)(Kc + row * 64 + blk * 8);
        s[0][ct] = __builtin_amdgcn_mfma_f32_16x16x32_bf16(aq[0][ks], kf, s[0][ct], 0, 0, 0);
        s[1][ct] = __builtin_amdgcn_mfma_f32_16x16x32_bf16(aq[1][ks], kf, s[1][ct], 0, 0, 0);
      }
    }
    __builtin_amdgcn_s_setprio(0);

    #pragma unroll
    for (int m = 0; m < 2; ++m) {
      #pragma unroll
      for (int b = 0; b < 4; ++b) {
        float rs = 0.f;
        #pragma unroll
        for (int ct = 0; ct < 4; ++ct) {
          const float p = exp2_fast(s[m][ct][b]);
          rs += p;
          Pw[(m * 16 + gs * 4 + b) * 72 + ct * 16 + rl] = (__bf16)p;
        }
        L[m][b] += rs;
      }
    }

    WAIT_LGKM();
    bf16x8 ap[2][2];
    #pragma unroll
    for (int m = 0; m < 2; ++m)
      #pragma unroll
      for (int ks = 0; ks < 2; ++ks)
        ap[m][ks] = *(const bf16x8*)(Pw + (m * 16 + rl) * 72 + ks * 32 + gs * 8);

    __builtin_amdgcn_s_setprio(1);
    #pragma unroll
    for (int dt = 0; dt < 4; ++dt) {
      #pragma unroll
      for (int ks = 0; ks < 2; ++ks) {
        const int row = dt * 16 + rl;
        const int blk = (ks * 4 + gs) ^ (row & 7);
        bf16x8 vf = *(const bf16x8*)(Vc + row * 64 + blk * 8);
        accO[0][dt] = __builtin_amdgcn_mfma_f32_16x16x32_bf16(ap[0][ks], vf, accO[0][dt], 0, 0, 0);
        accO[1][dt] = __builtin_amdgcn_mfma_f32_16x16x32_bf16(ap[1][ks], vf, accO[1][dt], 0, 0, 0);
      }
    }
    __builtin_amdgcn_s_setprio(0);

    S_BARRIER();
  }

  float invL[2][4];
  #pragma unroll
  for (int m = 0; m < 2; ++m)
    #pragma unroll
    for (int b = 0; b < 4; ++b) {
      float rs = L[m][b];
      #pragma unroll
      for (int off = 1; off < 16; off <<= 1) rs += __shfl_xor(rs, off, 16);
      invL[m][b] = 1.0f / rs;
    }

  const int batch = bh / 12, hh = bh - batch * 12;
  #pragma unroll
  for (int m = 0; m < 2; ++m) {
    const size_t rowbase = (size_t)batch * 1024 + qt * 128 + w * 32 + m * 16 + gs * 4;
    #pragma unroll
    for (int dt = 0; dt < 4; ++dt)
      #pragma unroll
      for (int b = 0; b < 4; ++b)
        Ob[(rowbase + b) * 768 + hh * 64 + dt * 16 + rl] = f32_to_fp8(accO[m][dt][b] * invL[m][b]);
  }
}

// ---------------- launch ----------------
extern "C" void kernel_launch(void* const* d_in, const int* in_sizes, int n_in,
                              void* d_out, int out_size, void* d_ws, size_t ws_size,
                              hipStream_t stream) {
  const float* x      = (const float*)d_in[0];
  const float* ln1_g  = (const float*)d_in[1];
  const float* ln1_b  = (const float*)d_in[2];
  const float* w_qkv  = (const float*)d_in[3];
  const float* w_proj = (const float*)d_in[4];
  const float* b_proj = (const float*)d_in[5];
  const float* ls1    = (const float*)d_in[6];
  const float* ln2_g  = (const float*)d_in[7];
  const float* ln2_b  = (const float*)d_in[8];
  const float* w_fc1  = (const float*)d_in[9];
  const float* b_fc1  = (const float*)d_in[10];
  const float* w_fc2  = (const float*)d_in[11];
  const float* b_fc2  = (const float*)d_in[12];
  const float* ls2    = (const float*)d_in[13];
  float* out = (float*)d_out;

  char* ws = (char*)d_ws;
  size_t off = 0;
  auto alloc = [&](size_t bytes) { char* p = ws + off; off += (bytes + 255) & ~(size_t)255; return p; };
  unsigned char* h1    = (unsigned char*)alloc(8192ull * 768);      // LN1 out (fp8); later attn_out (fp8)
  unsigned char* wqkv4 = (unsigned char*)alloc(2304ull * 384);
  unsigned char* wprj4 = (unsigned char*)alloc(768ull * 384);
  unsigned char* wfc14 = (unsigned char*)alloc(3072ull * 384);
  unsigned char* wfc24 = (unsigned char*)alloc(768ull * 1536);
  __bf16* Qb    = (__bf16*)alloc(8192ull * 768 * 2);
  __bf16* Kb    = (__bf16*)alloc(8192ull * 768 * 2);
  __bf16* Vt    = (__bf16*)alloc(8192ull * 768 * 2);
  float*  out1  = (float*)alloc(8192ull * 768 * 4);
  unsigned char* fc1o = (unsigned char*)alloc(8192ull * 3072);      // fp8
  unsigned char* h2   = (unsigned char*)alloc(8192ull * 768);       // LN2 out (fp8)

  constexpr unsigned int SC7 = 0x78787878u;   // e8m0 2^-7 (weights quantized at x128)
  constexpr unsigned int SC8 = 0x77777777u;   // e8m0 2^-8 (fc2 quantized at x256)

  ln_kernel<<<2048, 256, 0, stream>>>(x, ln1_g, ln1_b, h1);
  cast4_kernel<<<2048, 256, 0, stream>>>(w_qkv, w_proj, w_fc1, w_fc2,
                                         wqkv4, wprj4, wfc14, wfc24);

  gemm_kernel<0, 768, SC7><<<dim3(36, 64), 256, 0, stream>>>(h1, wqkv4,
      nullptr, nullptr, nullptr, nullptr, nullptr, Qb, Kb, Vt);

  attn_kernel<<<96 * 8, 256, 0, stream>>>(Qb, Kb, Vt, h1);  // h1 = attn_out (fp8) now

  gemm_kernel<1, 768, SC7><<<dim3(12, 64), 256, 0, stream>>>(h1, wprj4,
      b_proj, x, ls1, out1, nullptr, nullptr, nullptr, nullptr);

  ln_kernel<<<2048, 256, 0, stream>>>(out1, ln2_g, ln2_b, h2);

  gemm_kernel<2, 768, SC7><<<dim3(48, 64), 256, 0, stream>>>(h2, wfc14,
      b_fc1, nullptr, nullptr, nullptr, fc1o, nullptr, nullptr, nullptr);

  gemm_kernel<3, 3072, SC8><<<dim3(12, 64), 256, 0, stream>>>(fc1o, wfc24,
      b_fc2, out1, ls2, out, nullptr, nullptr, nullptr, nullptr);
}